// Round 4
// baseline (893.993 us; speedup 1.0000x reference)
//
#include <hip/hip_runtime.h>
#include <stdint.h>

// Problem dims
#define MROWS 32768   // B*T
#define TSEQ  1024
#define BBATCH 32
#define INDIM 1536
#define DDIM  768
#define NCAT  2304    // un_emb (768) + pw_x (768) + pw_y (768)

typedef short short8 __attribute__((ext_vector_type(8)));
typedef short short4v __attribute__((ext_vector_type(4)));
typedef float f32x4  __attribute__((ext_vector_type(4)));

__device__ __forceinline__ float b2f(ushort u) {
    union { uint32_t u; float f; } x; x.u = ((uint32_t)u) << 16; return x.f;
}
__device__ __forceinline__ ushort f2b(float f) {
    union { float f; uint32_t u; } x; x.f = f;
    uint32_t r = x.u + 0x7fffu + ((x.u >> 16) & 1u);
    return (ushort)(r >> 16);
}

__device__ __forceinline__ void cvt4(const float* __restrict__ in, ushort* __restrict__ out, int i) {
    float4 v = ((const float4*)in)[i];
    ushort4 o;
    o.x = f2b(v.x); o.y = f2b(v.y); o.z = f2b(v.z); o.w = f2b(v.w);
    ((ushort4*)out)[i] = o;
}

// ---------------- ALL conversions + bias concat + accumulator zeroing, ONE launch ----------------
#define C0 12582912   // x -> X16
#define C1 13172736   // fc1_w -> W1
#define C2 13467648   // fc2_w -> W2
#define C3 13615104   // un_emb_w -> W3[0]
#define C4 13762560   // pw_x_w -> W3[1]
#define C5 13910016   // pw_y_w -> W3[2]
#define C6 13910592   // biases -> B3
#define C7 13916736   // zero YBAR
#define C8 13922880   // zero d_out
#define C9 13947456   // zero SE/SX/SY (contiguous)
__global__ void cvt_all(const float* __restrict__ x,
                        const float* __restrict__ fc1_w, const float* __restrict__ fc2_w,
                        const float* __restrict__ w3a, const float* __restrict__ w3b,
                        const float* __restrict__ w3c,
                        const float* __restrict__ ba, const float* __restrict__ bb,
                        const float* __restrict__ bc,
                        ushort* __restrict__ X16, ushort* __restrict__ W1,
                        ushort* __restrict__ W2, ushort* __restrict__ W3,
                        float* __restrict__ B3, float* __restrict__ ybar_z,
                        float* __restrict__ out_z, float* __restrict__ stats_z)
{
    int i = blockIdx.x * 256 + threadIdx.x;  // float4 index
    float4 z = {0.f, 0.f, 0.f, 0.f};
    if (i < C0)       cvt4(x, X16, i);
    else if (i < C1)  cvt4(fc1_w, W1, i - C0);
    else if (i < C2)  cvt4(fc2_w, W2, i - C1);
    else if (i < C3)  cvt4(w3a, W3,           i - C2);
    else if (i < C4)  cvt4(w3b, W3 + 589824,  i - C3);
    else if (i < C5)  cvt4(w3c, W3 + 1179648, i - C4);
    else if (i < C6) {
        int j = i - C5;  // 0..575 float4s of B3 (2304 floats)
        const float* src = (j < 192) ? ba : (j < 384) ? bb : bc;
        int off = (j < 192) ? j : (j < 384) ? (j - 192) : (j - 384);
        ((float4*)B3)[j] = ((const float4*)src)[off];
    }
    else if (i < C7)  ((float4*)ybar_z)[i - C6] = z;
    else if (i < C8)  ((float4*)out_z)[i - C7] = z;
    else if (i < C9)  ((float4*)stats_z)[i - C8] = z;
}

// ---------------- bf16 GEMM: C[M,N] = A[M,K] * B[N,K]^T + bias, optional relu on cols < relu_ncols
// R11: 1-barrier K-loop + B direct from L2.  256x256 tile, 512 thr = 8 waves
// (2m x 4n), per-wave 128x64 output (acc[8][4] of 16x16x32 MFMA). BK=64.
// A (HBM-cold stream): LDS ring 3 x 32KB = 96KB, staged TWO K-tiles ahead with
//   global_load_lds (R3-verified staging map + XOR granule swizzle:
//   coalesced 64B/4lanes AND conflict-free ds_read_b128).
// B (L2-hot weights): NO LDS — frags loaded global->VGPR (compiler-tracked),
//   double-buffered one K-tile ahead. Frag = 16 rows x 16B contiguous, value
//   layout identical to the LDS path. Cuts LDS traffic 256->160 KB/K-tile and
//   moves B bytes to the parallel VMEM/L2 pipe.
// ONE barrier per K-tile, NO lgkmcnt(0) drains: every ds_read is consumed by
//   an MFMA (compiler emits fine-grained lgkm waits), so all reads of slot
//   t%3 are retired before the iter-t barrier; the next write to that slot is
//   issued in iter t+1 (stage t+3) — one full barrier later. Cross-wave
//   visibility: each wave's own counted vmcnt before the shared barrier.
// vmcnt accounting (per-wave FIFO; kept set = 12 newest ops, robust to
//   in-region reorder): end of iter t keeps {A(t+2):4, B(t+1):8} -> vmcnt(12);
//   t==kT-2 -> vmcnt(8); last iter none. Prologue drains vmcnt(0) once (cold).
// setprio(1) around the MFMA cluster (T5).
// Optional fused row-stats (GEMM3): per-row SE/SX/SY atomics in epilogue.
// Requires (M/256)%8==0, N%256==0, K%128==0 (kT even), K/64>=4.
__global__ __launch_bounds__(512, 2)
void gemm_bt(const ushort* __restrict__ A, const ushort* __restrict__ Bm,
             const float* __restrict__ bias, ushort* __restrict__ C,
             int M, int N, int K, int relu_ncols,
             const float* __restrict__ urw, float* __restrict__ SE,
             float* __restrict__ SX, float* __restrict__ SY)
{
    // A ring: 3 slots x 16384 ushorts (each slot: 2 ksteps x 16 segs x 512) = 96KB
    __shared__ __align__(16) ushort lds[49152];

    const int tid  = threadIdx.x;
    const int lane = tid & 63, wave = tid >> 6;    // 8 waves
    const int wm = wave >> 2, wn = wave & 3;       // 2 x 4 wave grid
    const int quad = lane >> 4, r16 = lane & 15;

    // XCD-pinned block swizzle (bijective: (M/256)=128 is a multiple of 8)
    const int ntiles = N >> 8;
    const int xcd = blockIdx.x & 7;
    const int j   = blockIdx.x >> 3;
    const int g   = j / ntiles;            // m-group within this XCD
    const int n_t = j - g * ntiles;
    const int m_t = xcd + (g << 3);
    const int m0 = m_t * 256, n0 = n_t * 256;

    // staging lane map: row = lane>>2 within a 16-row segment; granule permuted
    const int srow = lane >> 2;
    const int g8   = (((lane & 3) ^ ((srow >> 1) & 3)) << 3);  // src granule (ushorts)
    // fragment-read granule offset: row r16, stored slot quad^((r16>>1)&3)
    const int goff = (r16 << 5) + ((quad ^ ((r16 >> 1) & 3)) << 3);

    // A staging (R3-verified): wave w, piece MH covers rows MH*64+(w&3)*16+srow+(w>>2)*128
    const ushort* pA = A + (size_t)(m0 + (wave & 3) * 16 + srow + (wave >> 2) * 128) * K + g8;
    const int segA = (((wave >> 2) * 8 + (wave & 3)) << 9) + lane * 8;

    // B direct-load base: row = n0 + wn*64 + j2*16 + r16, k = t*64 + ks*32 + quad*8
    const ushort* pBg = Bm + (size_t)(n0 + wn * 64 + r16) * K + quad * 8;

    const int kT = K >> 6;                 // K-tiles of 64 (even)

#define STG(p, off) __builtin_amdgcn_global_load_lds( \
        (const __attribute__((address_space(1))) void*)(p), \
        (__attribute__((address_space(3))) void*)&lds[off], 16, 0, 0)
#define STAGE_A(tt, MH) do { \
        const ushort* s_ = pA + (size_t)(MH) * 64 * K + (size_t)(tt) * 64; \
        const int d_ = ((tt) % 3) * 16384 + (MH) * 2048 + segA; \
        STG(s_,      d_); \
        STG(s_ + 32, d_ + 8192); } while (0)

    // prologue: stage A(0), A(1); load B(0); full drain once (cold HBM anyway)
    STAGE_A(0, 0); STAGE_A(0, 1);
    STAGE_A(1, 0); STAGE_A(1, 1);
    f32x4 acc[8][4] = {};
    short8 bfA[2][4], bfB[2][4];
#pragma unroll
    for (int ks = 0; ks < 2; ++ks)
#pragma unroll
        for (int j2 = 0; j2 < 4; ++j2)
            bfA[ks][j2] = *(const short8*)(pBg + (size_t)(j2 * 16) * K + ks * 32);
    asm volatile("s_waitcnt vmcnt(0)" ::: "memory");
    asm volatile("s_barrier" ::: "memory");

    // one K-tile: af reads (LDS) + A-stage(t+2) + B-prefetch(t+1)->bfn + 64 MFMA
    // (compiler-scheduled fine lgkm/vm waits) + counted vmcnt + ONE barrier.
#define ITER(t, bfc, bfn) do { \
    const int aB_ = ((t) % 3) * 16384; \
    short8 af0_[2][4], af1_[2][4]; \
    _Pragma("unroll") for (int ks_ = 0; ks_ < 2; ++ks_) \
    _Pragma("unroll") for (int i_ = 0; i_ < 4; ++i_) \
        af0_[ks_][i_] = *(const short8*)&lds[aB_ + ks_ * 8192 + (wm * 8 + i_) * 512 + goff]; \
    if ((t) + 2 < kT) { STAGE_A((t) + 2, 0); STAGE_A((t) + 2, 1); } \
    if ((t) + 1 < kT) { \
        _Pragma("unroll") for (int ks_ = 0; ks_ < 2; ++ks_) \
        _Pragma("unroll") for (int j_ = 0; j_ < 4; ++j_) \
            bfn[ks_][j_] = *(const short8*)(pBg + (size_t)(j_ * 16) * K + ((t) + 1) * 64 + ks_ * 32); } \
    __builtin_amdgcn_s_setprio(1); \
    _Pragma("unroll") for (int i_ = 0; i_ < 4; ++i_) \
    _Pragma("unroll") for (int j_ = 0; j_ < 4; ++j_) { \
        acc[i_][j_] = __builtin_amdgcn_mfma_f32_16x16x32_bf16(af0_[0][i_], bfc[0][j_], acc[i_][j_], 0, 0, 0); \
        acc[i_][j_] = __builtin_amdgcn_mfma_f32_16x16x32_bf16(af0_[1][i_], bfc[1][j_], acc[i_][j_], 0, 0, 0); } \
    _Pragma("unroll") for (int ks_ = 0; ks_ < 2; ++ks_) \
    _Pragma("unroll") for (int i_ = 0; i_ < 4; ++i_) \
        af1_[ks_][i_] = *(const short8*)&lds[aB_ + ks_ * 8192 + (wm * 8 + 4 + i_) * 512 + goff]; \
    _Pragma("unroll") for (int i_ = 0; i_ < 4; ++i_) \
    _Pragma("unroll") for (int j_ = 0; j_ < 4; ++j_) { \
        acc[4 + i_][j_] = __builtin_amdgcn_mfma_f32_16x16x32_bf16(af1_[0][i_], bfc[0][j_], acc[4 + i_][j_], 0, 0, 0); \
        acc[4 + i_][j_] = __builtin_amdgcn_mfma_f32_16x16x32_bf16(af1_[1][i_], bfc[1][j_], acc[4 + i_][j_], 0, 0, 0); } \
    __builtin_amdgcn_s_setprio(0); \
    if ((t) + 2 < kT)      asm volatile("s_waitcnt vmcnt(12)" ::: "memory"); \
    else if ((t) + 1 < kT) asm volatile("s_waitcnt vmcnt(8)" ::: "memory"); \
    if ((t) + 1 < kT)      asm volatile("s_barrier" ::: "memory"); \
} while (0)

    for (int t = 0; t < kT; t += 2) {   // kT even: named reg double-buffer, no dyn idx
        ITER(t,     bfA, bfB);
        ITER(t + 1, bfB, bfA);
    }
#undef ITER
#undef STAGE_A
#undef STG

    // epilogue: C/D layout col = lane&15, row = quad*4 + reg  [m89-verified]
    // jj-innermost store order: 4 adjacent 32B stores per row -> L2 merges lines.
    const bool stats = (urw != nullptr);
    const int sec = n0 / DDIM;           // 0=e, 1=xe, 2=ye (GEMM3 only)
    float bv[4], uwv[4];
    bool dr[4];
#pragma unroll
    for (int jj = 0; jj < 4; ++jj) {
        int gn = n0 + wn * 64 + jj * 16 + r16;
        bv[jj] = bias[gn];
        dr[jj] = gn < relu_ncols;
        uwv[jj] = (stats && sec == 0) ? urw[gn] : 0.f;
    }
    float st[8][4] = {};                 // per-(i,rr) row partials
#pragma unroll
    for (int i = 0; i < 8; ++i) {
#pragma unroll
        for (int rr = 0; rr < 4; ++rr) {
            size_t base = (size_t)(m0 + wm * 128 + i * 16 + quad * 4 + rr) * N + n0 + wn * 64 + r16;
#pragma unroll
            for (int jj = 0; jj < 4; ++jj) {
                float v = acc[i][jj][rr] + bv[jj];
                if (dr[jj]) v = fmaxf(v, 0.f);
                C[base + jj * 16] = f2b(v);
                if (stats) st[i][rr] += (sec == 0) ? v * uwv[jj] : v * v;
            }
        }
    }
    if (stats) {
#pragma unroll
        for (int i = 0; i < 8; ++i)
#pragma unroll
            for (int rr = 0; rr < 4; ++rr) {
                float v = st[i][rr];
                v += __shfl_xor(v, 1, 64);
                v += __shfl_xor(v, 2, 64);
                v += __shfl_xor(v, 4, 64);
                v += __shfl_xor(v, 8, 64);
                st[i][rr] = v;
            }
        if (r16 == 0) {
            float* dst = (sec == 0) ? SE : (sec == 1) ? SX : SY;
#pragma unroll
            for (int i = 0; i < 8; ++i)
#pragma unroll
                for (int rr = 0; rr < 4; ++rr)
                    atomicAdd(&dst[m0 + wm * 128 + i * 16 + quad * 4 + rr], st[i][rr]);
        }
    }
}

// ---------------- ybar[b,d] += partial over a 32-step s chunk ----------------
// ybar[b,d] = (1/T) * sum_s ye[b,s,d] / max(||ye[b,s]||,1e-12); grid (B, 32).
__global__ void ybar_k(const ushort* __restrict__ G3, const float* __restrict__ sy,
                       float* __restrict__ ybar)
{
    int b = blockIdx.x, s0 = blockIdx.y * 32;
    int tid = threadIdx.x;
    __shared__ float sr[32];
    if (tid < 32) {
        float v = sy[b * TSEQ + s0 + tid];
        sr[tid] = (1.0f / TSEQ) / fmaxf(sqrtf(v), 1e-12f);
    }
    __syncthreads();
    float a0 = 0.f, a1 = 0.f, a2 = 0.f;
#pragma unroll 8
    for (int s = 0; s < 32; ++s) {
        const ushort* row = G3 + (size_t)(b * TSEQ + s0 + s) * NCAT + 2 * DDIM;
        float w = sr[s];
        a0 += b2f(row[tid])       * w;
        a1 += b2f(row[tid + 256]) * w;
        a2 += b2f(row[tid + 512]) * w;
    }
    atomicAdd(&ybar[b * DDIM + tid],       a0);
    atomicAdd(&ybar[b * DDIM + tid + 256], a1);
    atomicAdd(&ybar[b * DDIM + tid + 512], a2);
}

// ---------------- scores: wave-per-row, 4 rows/block (8192 blocks) ----------------
// scores[m] = rw0*(SE[m]+urb) + rw1 * dot(xe[m],ybar[b]) / max(sqrt(SX[m]),1e-12)
__global__ void pw_scores_k(const ushort* __restrict__ G3, const float* __restrict__ ybar,
                            const float* __restrict__ SE, const float* __restrict__ SX,
                            const float* __restrict__ urb, const float* __restrict__ red_w,
                            float* __restrict__ scores)
{
    int wv = threadIdx.x >> 6, lane = threadIdx.x & 63;
    int m = blockIdx.x * 4 + wv;
    int b = m >> 10;
    const ushort* xe = G3 + (size_t)m * NCAT + DDIM;
    const float4* yb = (const float4*)(ybar + b * DDIM);
    float s = 0.f;
#pragma unroll
    for (int c0 = 0; c0 < 3; ++c0) {
        int c = lane + c0 * 64;
        short4v v = *(const short4v*)(xe + c * 4);
        float4 yv = yb[c];
        s += b2f((ushort)v[0]) * yv.x + b2f((ushort)v[1]) * yv.y
           + b2f((ushort)v[2]) * yv.z + b2f((ushort)v[3]) * yv.w;
    }
#pragma unroll
    for (int off = 32; off; off >>= 1) s += __shfl_xor(s, off, 64);
    if (lane == 0) {
        float rnx = 1.f / fmaxf(sqrtf(SX[m]), 1e-12f);
        scores[m] = red_w[0] * (SE[m] + urb[0]) + red_w[1] * (rnx * s);
    }
}

// ---------------- out (with inline softmax): grid (B, 32) ----------------
// Each block recomputes batch-b softmax stats from scores (4 KB, L2-hit), then
// accumulates its 32-t chunk of out[b,:] = sum_t softmax(scores)[t] * u[b,t,:].
__global__ void out_sm_k(const ushort* __restrict__ U16, const float* __restrict__ scores,
                         float* __restrict__ out)
{
    int b = blockIdx.x, t0 = blockIdx.y * 32;
    int tid = threadIdx.x;
    int lane = tid & 63, wv = tid >> 6;
    __shared__ float red[8];
    __shared__ float sw[32];

    // block-wide softmax stats over scores[b, 0..1023]
    float v[4];
    float lm = -1e30f;
#pragma unroll
    for (int i = 0; i < 4; ++i) {
        v[i] = scores[b * TSEQ + i * 256 + tid];
        lm = fmaxf(lm, v[i]);
    }
#pragma unroll
    for (int off = 32; off; off >>= 1) lm = fmaxf(lm, __shfl_xor(lm, off, 64));
    if (lane == 0) red[wv] = lm;
    __syncthreads();
    float smax = fmaxf(fmaxf(red[0], red[1]), fmaxf(red[2], red[3]));
    float ls = 0.f;
#pragma unroll
    for (int i = 0; i < 4; ++i) ls += expf(v[i] - smax);
#pragma unroll
    for (int off = 32; off; off >>= 1) ls += __shfl_xor(ls, off, 64);
    if (lane == 0) red[4 + wv] = ls;
    __syncthreads();
    float inv = 1.f / (red[4] + red[5] + red[6] + red[7]);

    if (tid < 32) sw[tid] = expf(scores[b * TSEQ + t0 + tid] - smax) * inv;
    __syncthreads();

    float a0 = 0.f, a1 = 0.f, a2 = 0.f;
#pragma unroll 8
    for (int t = 0; t < 32; ++t) {
        const ushort* row = U16 + (size_t)(b * TSEQ + t0 + t) * DDIM;
        float w = sw[t];
        a0 += b2f(row[tid])       * w;
        a1 += b2f(row[tid + 256]) * w;
        a2 += b2f(row[tid + 512]) * w;
    }
    atomicAdd(&out[b * DDIM + tid],       a0);
    atomicAdd(&out[b * DDIM + tid + 256], a1);
    atomicAdd(&out[b * DDIM + tid + 512], a2);
}

// ---------------- workspace layout (bytes) ----------------
// G3 (e|xe|ye bf16, 151 MB) aliases the X16+H16 region (dead after GEMM2).
static const size_t O_X16   = 0;            // 32768*1536*2 = 100663296
static const size_t O_H16   = 100663296;    // 100663296
static const size_t O_G3    = 0;            // 150994944 (alias)
static const size_t O_U16   = 201326592;    // 50331648
static const size_t O_W1    = 251658240;    // 4718592
static const size_t O_W2    = 256376832;    // 2359296
static const size_t O_W3    = 258736128;    // 3538944
static const size_t O_B3    = 262275072;    // 9216
static const size_t O_SE    = 262284288;    // 131072  (SE/SX/SY contiguous)
static const size_t O_SX    = 262415360;    // 131072
static const size_t O_SY    = 262546432;    // 131072
static const size_t O_SCORE = 262677504;    // 131072
static const size_t O_YBAR  = 262939648;    // 98304
// total: 263037952 bytes (~263 MB)

extern "C" void kernel_launch(void* const* d_in, const int* in_sizes, int n_in,
                              void* d_out, int out_size, void* d_ws, size_t ws_size,
                              hipStream_t stream)
{
    const float* x        = (const float*)d_in[0];
    const float* fc1_w    = (const float*)d_in[1];
    const float* fc1_b    = (const float*)d_in[2];
    const float* fc2_w    = (const float*)d_in[3];
    const float* fc2_b    = (const float*)d_in[4];
    const float* un_emb_w = (const float*)d_in[5];
    const float* un_emb_b = (const float*)d_in[6];
    const float* un_red_w = (const float*)d_in[7];
    const float* un_red_b = (const float*)d_in[8];
    const float* pw_x_w   = (const float*)d_in[9];
    const float* pw_x_b   = (const float*)d_in[10];
    const float* pw_y_w   = (const float*)d_in[11];
    const float* pw_y_b   = (const float*)d_in[12];
    const float* red_w    = (const float*)d_in[13];

    char* ws = (char*)d_ws;
    ushort* X16 = (ushort*)(ws + O_X16);
    ushort* H16 = (ushort*)(ws + O_H16);
    ushort* G3  = (ushort*)(ws + O_G3);
    ushort* U16 = (ushort*)(ws + O_U16);
    ushort* W1  = (ushort*)(ws + O_W1);
    ushort* W2  = (ushort*)(ws + O_W2);
    ushort* W3  = (ushort*)(ws + O_W3);
    float*  B3  = (float*)(ws + O_B3);
    float*  SE  = (float*)(ws + O_SE);
    float*  SX  = (float*)(ws + O_SX);
    float*  SY  = (float*)(ws + O_SY);
    float*  SCORES = (float*)(ws + O_SCORE);
    float*  YBAR = (float*)(ws + O_YBAR);

    // --- one conversion/zeroing pass ---
    cvt_all<<<54483, 256, 0, stream>>>(x, fc1_w, fc2_w, un_emb_w, pw_x_w, pw_y_w,
                                       un_emb_b, pw_x_b, pw_y_b,
                                       X16, W1, W2, W3, B3, YBAR, (float*)d_out, SE);

    // --- GEMM chain (1-D grid, XCD-pinned swizzle inside kernel), 256^2 tiles ---
    gemm_bt<<<(MROWS / 256) * (INDIM / 256), 512, 0, stream>>>(
        X16, W1, fc1_b, H16, MROWS, INDIM, INDIM, INDIM,
        nullptr, nullptr, nullptr, nullptr);
    gemm_bt<<<(MROWS / 256) * (DDIM / 256), 512, 0, stream>>>(
        H16, W2, fc2_b, U16, MROWS, DDIM, INDIM, 0,
        nullptr, nullptr, nullptr, nullptr);
    gemm_bt<<<(MROWS / 256) * (NCAT / 256), 512, 0, stream>>>(
        U16, W3, B3, G3, MROWS, NCAT, DDIM, DDIM,
        un_red_w, SE, SX, SY);

    // --- tail: ybar -> scores -> out(+softmax), independent small launches ---
    ybar_k<<<dim3(BBATCH, 32), 256, 0, stream>>>(G3, SY, YBAR);
    pw_scores_k<<<MROWS / 4, 256, 0, stream>>>(G3, YBAR, SE, SX, un_red_b, red_w, SCORES);
    out_sm_k<<<dim3(BBATCH, 32), 256, 0, stream>>>(U16, SCORES, (float*)d_out);
}

// Round 5
// 700.263 us; speedup vs baseline: 1.2767x; 1.2767x over previous
//
#include <hip/hip_runtime.h>
#include <stdint.h>

// Problem dims
#define MROWS 32768   // B*T
#define TSEQ  1024
#define BBATCH 32
#define INDIM 1536
#define DDIM  768
#define NCAT  2304    // un_emb (768) + pw_x (768) + pw_y (768)

typedef short short8 __attribute__((ext_vector_type(8)));
typedef short short4v __attribute__((ext_vector_type(4)));
typedef float f32x4  __attribute__((ext_vector_type(4)));

__device__ __forceinline__ float b2f(ushort u) {
    union { uint32_t u; float f; } x; x.u = ((uint32_t)u) << 16; return x.f;
}
__device__ __forceinline__ ushort f2b(float f) {
    union { float f; uint32_t u; } x; x.f = f;
    uint32_t r = x.u + 0x7fffu + ((x.u >> 16) & 1u);
    return (ushort)(r >> 16);
}

__device__ __forceinline__ void cvt4(const float* __restrict__ in, ushort* __restrict__ out, int i) {
    float4 v = ((const float4*)in)[i];
    ushort4 o;
    o.x = f2b(v.x); o.y = f2b(v.y); o.z = f2b(v.z); o.w = f2b(v.w);
    ((ushort4*)out)[i] = o;
}

// ---------------- ALL conversions + bias concat + accumulator zeroing, ONE launch ----------------
#define C0 12582912   // x -> X16
#define C1 13172736   // fc1_w -> W1
#define C2 13467648   // fc2_w -> W2
#define C3 13615104   // un_emb_w -> W3[0]
#define C4 13762560   // pw_x_w -> W3[1]
#define C5 13910016   // pw_y_w -> W3[2]
#define C6 13910592   // biases -> B3
#define C7 13916736   // zero YBAR
#define C8 13922880   // zero d_out
#define C9 13947456   // zero SE/SX/SY (contiguous)
__global__ void cvt_all(const float* __restrict__ x,
                        const float* __restrict__ fc1_w, const float* __restrict__ fc2_w,
                        const float* __restrict__ w3a, const float* __restrict__ w3b,
                        const float* __restrict__ w3c,
                        const float* __restrict__ ba, const float* __restrict__ bb,
                        const float* __restrict__ bc,
                        ushort* __restrict__ X16, ushort* __restrict__ W1,
                        ushort* __restrict__ W2, ushort* __restrict__ W3,
                        float* __restrict__ B3, float* __restrict__ ybar_z,
                        float* __restrict__ out_z, float* __restrict__ stats_z)
{
    int i = blockIdx.x * 256 + threadIdx.x;  // float4 index
    float4 z = {0.f, 0.f, 0.f, 0.f};
    if (i < C0)       cvt4(x, X16, i);
    else if (i < C1)  cvt4(fc1_w, W1, i - C0);
    else if (i < C2)  cvt4(fc2_w, W2, i - C1);
    else if (i < C3)  cvt4(w3a, W3,           i - C2);
    else if (i < C4)  cvt4(w3b, W3 + 589824,  i - C3);
    else if (i < C5)  cvt4(w3c, W3 + 1179648, i - C4);
    else if (i < C6) {
        int j = i - C5;  // 0..575 float4s of B3 (2304 floats)
        const float* src = (j < 192) ? ba : (j < 384) ? bb : bc;
        int off = (j < 192) ? j : (j < 384) ? (j - 192) : (j - 384);
        ((float4*)B3)[j] = ((const float4*)src)[off];
    }
    else if (i < C7)  ((float4*)ybar_z)[i - C6] = z;
    else if (i < C8)  ((float4*)out_z)[i - C7] = z;
    else if (i < C9)  ((float4*)stats_z)[i - C8] = z;
}

// ---------------- bf16 GEMM: C[M,N] = A[M,K] * B[N,K]^T + bias, optional relu on cols < relu_ncols
// R12 = R3's verified LDS layout/staging (A AND B via global_load_lds) +
//       R11's single-barrier K-loop (R3's 8 barriers + 8 lgkmcnt(0) drains
//       per K-tile were ~3000 of its 5870 cyc/K-tile).
// 256x256 tile, 512 thr = 8 waves (2m x 4n), per-wave 128x64 (acc[8][4]). BK=64.
// LDS 160KB: A ring 3 x 32KB (slot t%3, staged TWO tiles ahead — HBM stream);
//            B ring 2 x 32KB (slot t&1, staged ONE tile ahead — L2-hot weights).
// ONE barrier + ONE counted vmcnt per K-tile, NO lgkm drains (compiler emits
// fine-grained lgkm waits between ds_read and consuming MFMA).
// Race-freedom: slot written in iter t was last READ in iter t-1 (A: (t+2)%3 ==
// (t-1)%3; B: (t+1)&1 == (t-1)&1); those ds_reads retire before that wave's
// MFMAs, which precede the end-of-(t-1) barrier; stages are issued after it.
// Visibility: issue B(t+1) BEFORE A(t+2); end-of-iter vmcnt(4) keeps exactly
// A(t+2) (4 newest per-wave FIFO entries) and retires {A(t+1), B(t+1)} -> all
// data read in iter t+1 is resident. Tail: t==kT-2 -> vmcnt(0); last iter none.
// Granule swizzle (R3/R4-verified): coalesced 64B/4lanes staging AND
// conflict-free ds_read_b128 (SQ_LDS_BANK_CONFLICT == 0).
// setprio(1) around MFMA clusters (T5). Fused row-stats for GEMM3 in epilogue.
// Requires (M/256)%8==0, N%256==0, K%64==0, K/64>=3.
__global__ __launch_bounds__(512, 2)
void gemm_bt(const ushort* __restrict__ A, const ushort* __restrict__ Bm,
             const float* __restrict__ bias, ushort* __restrict__ C,
             int M, int N, int K, int relu_ncols,
             const float* __restrict__ urw, float* __restrict__ SE,
             float* __restrict__ SX, float* __restrict__ SY)
{
    // [A: 3 x 16384u][B: 2 x 16384u] = 81920 ushorts = 160 KB
    __shared__ __align__(16) ushort lds[81920];

    const int tid  = threadIdx.x;
    const int lane = tid & 63, wave = tid >> 6;    // 8 waves
    const int wm = wave >> 2, wn = wave & 3;       // 2 x 4 wave grid
    const int quad = lane >> 4, r16 = lane & 15;

    // XCD-pinned block swizzle (bijective: (M/256)=128 is a multiple of 8)
    const int ntiles = N >> 8;
    const int xcd = blockIdx.x & 7;
    const int j   = blockIdx.x >> 3;
    const int g   = j / ntiles;            // m-group within this XCD
    const int n_t = j - g * ntiles;
    const int m_t = xcd + (g << 3);
    const int m0 = m_t * 256, n0 = n_t * 256;

    // staging lane map: row = lane>>2 within a 16-row segment; granule permuted
    const int srow = lane >> 2;
    const int g8   = (((lane & 3) ^ ((srow >> 1) & 3)) << 3);  // src granule (ushorts)
    // fragment-read granule offset: row r16, stored slot quad^((r16>>1)&3)
    const int goff = (r16 << 5) + ((quad ^ ((r16 >> 1) & 3)) << 3);

    // A staging (R3-verified): wave w, piece MH covers rows MH*64+(w&3)*16+srow+(w>>2)*128
    const ushort* pA = A + (size_t)(m0 + (wave & 3) * 16 + srow + (wave >> 2) * 128) * K + g8;
    const int segA = (((wave >> 2) * 8 + (wave & 3)) << 9) + lane * 8;
    // B staging (R3-verified): wave w, piece NH covers rows (w>>1)*64+NH*32+(w&1)*16+srow
    const ushort* pB = Bm + (size_t)(n0 + (wave >> 1) * 64 + (wave & 1) * 16 + srow) * K + g8;
    const int segB = (((wave >> 1) * 4 + (wave & 1)) << 9) + lane * 8;

    const int kT = K >> 6;                 // K-tiles of 64

#define STG(p, off) __builtin_amdgcn_global_load_lds( \
        (const __attribute__((address_space(1))) void*)(p), \
        (__attribute__((address_space(3))) void*)&lds[off], 16, 0, 0)
#define STAGE_A(tt, MH) do { \
        const ushort* s_ = pA + (size_t)(MH) * 64 * K + (size_t)(tt) * 64; \
        const int d_ = ((tt) % 3) * 16384 + (MH) * 2048 + segA; \
        STG(s_,      d_); \
        STG(s_ + 32, d_ + 8192); } while (0)
#define STAGE_B(tt, NH) do { \
        const ushort* s_ = pB + (size_t)(NH) * 32 * K + (size_t)(tt) * 64; \
        const int d_ = 49152 + ((tt) & 1) * 16384 + (NH) * 1024 + segB; \
        STG(s_,      d_); \
        STG(s_ + 32, d_ + 8192); } while (0)

    // prologue: A(0) [4], B(0) [4], A(1) [4]; vmcnt(4) keeps A(1) in flight
    STAGE_A(0, 0); STAGE_A(0, 1);
    STAGE_B(0, 0); STAGE_B(0, 1);
    STAGE_A(1, 0); STAGE_A(1, 1);
    asm volatile("s_waitcnt vmcnt(4)" ::: "memory");
    asm volatile("s_barrier" ::: "memory");

    f32x4 acc[8][4] = {};

    for (int t = 0; t < kT; ++t) {
        const int aB = (t % 3) * 16384;
        const int bB = 49152 + (t & 1) * 16384;
        short8 af0[2][4], af1[2][4], bf[2][4];

        // frag reads for this K-tile: A-MH0 (8) + B all (8)
#pragma unroll
        for (int ks = 0; ks < 2; ++ks) {
#pragma unroll
            for (int i = 0; i < 4; ++i)
                af0[ks][i] = *(const short8*)&lds[aB + ks * 8192 + (wm * 8 + i) * 512 + goff];
#pragma unroll
            for (int jj = 0; jj < 4; ++jj)
                bf[ks][jj] = *(const short8*)&lds[bB + ks * 8192 + (wn * 4 + jj) * 512 + goff];
        }
        // stage next tiles: B(t+1) FIRST, then A(t+2) (vmcnt FIFO accounting)
        if (t + 1 < kT) { STAGE_B(t + 1, 0); STAGE_B(t + 1, 1); }
        if (t + 2 < kT) { STAGE_A(t + 2, 0); STAGE_A(t + 2, 1); }

        __builtin_amdgcn_s_setprio(1);
#pragma unroll
        for (int i = 0; i < 4; ++i)
#pragma unroll
            for (int jj = 0; jj < 4; ++jj) {
                acc[i][jj] = __builtin_amdgcn_mfma_f32_16x16x32_bf16(af0[0][i], bf[0][jj], acc[i][jj], 0, 0, 0);
                acc[i][jj] = __builtin_amdgcn_mfma_f32_16x16x32_bf16(af0[1][i], bf[1][jj], acc[i][jj], 0, 0, 0);
            }
        __builtin_amdgcn_s_setprio(0);

        // A-MH1 frags (8), second MFMA cluster
#pragma unroll
        for (int ks = 0; ks < 2; ++ks)
#pragma unroll
            for (int i = 0; i < 4; ++i)
                af1[ks][i] = *(const short8*)&lds[aB + ks * 8192 + (wm * 8 + 4 + i) * 512 + goff];

        __builtin_amdgcn_s_setprio(1);
#pragma unroll
        for (int i = 0; i < 4; ++i)
#pragma unroll
            for (int jj = 0; jj < 4; ++jj) {
                acc[4 + i][jj] = __builtin_amdgcn_mfma_f32_16x16x32_bf16(af1[0][i], bf[0][jj], acc[4 + i][jj], 0, 0, 0);
                acc[4 + i][jj] = __builtin_amdgcn_mfma_f32_16x16x32_bf16(af1[1][i], bf[1][jj], acc[4 + i][jj], 0, 0, 0);
            }
        __builtin_amdgcn_s_setprio(0);

        // ONE counted vmcnt + ONE barrier per K-tile
        if (t + 2 < kT)      asm volatile("s_waitcnt vmcnt(4)" ::: "memory");
        else if (t + 1 < kT) asm volatile("s_waitcnt vmcnt(0)" ::: "memory");
        if (t + 1 < kT)      asm volatile("s_barrier" ::: "memory");
    }
#undef STAGE_A
#undef STAGE_B
#undef STG

    // epilogue: C/D layout col = lane&15, row = quad*4 + reg  [m89-verified]
    // jj-innermost store order (R4-verified: WRITE_SIZE ~ideal).
    const bool stats = (urw != nullptr);
    const int sec = n0 / DDIM;           // 0=e, 1=xe, 2=ye (GEMM3 only)
    float bv[4], uwv[4];
    bool dr[4];
#pragma unroll
    for (int jj = 0; jj < 4; ++jj) {
        int gn = n0 + wn * 64 + jj * 16 + r16;
        bv[jj] = bias[gn];
        dr[jj] = gn < relu_ncols;
        uwv[jj] = (stats && sec == 0) ? urw[gn] : 0.f;
    }
    float st[8][4] = {};                 // per-(i,rr) row partials
#pragma unroll
    for (int i = 0; i < 8; ++i) {
#pragma unroll
        for (int rr = 0; rr < 4; ++rr) {
            size_t base = (size_t)(m0 + wm * 128 + i * 16 + quad * 4 + rr) * N + n0 + wn * 64 + r16;
#pragma unroll
            for (int jj = 0; jj < 4; ++jj) {
                float v = acc[i][jj][rr] + bv[jj];
                if (dr[jj]) v = fmaxf(v, 0.f);
                C[base + jj * 16] = f2b(v);
                if (stats) st[i][rr] += (sec == 0) ? v * uwv[jj] : v * v;
            }
        }
    }
    if (stats) {
#pragma unroll
        for (int i = 0; i < 8; ++i)
#pragma unroll
            for (int rr = 0; rr < 4; ++rr) {
                float v = st[i][rr];
                v += __shfl_xor(v, 1, 64);
                v += __shfl_xor(v, 2, 64);
                v += __shfl_xor(v, 4, 64);
                v += __shfl_xor(v, 8, 64);
                st[i][rr] = v;
            }
        if (r16 == 0) {
            float* dst = (sec == 0) ? SE : (sec == 1) ? SX : SY;
#pragma unroll
            for (int i = 0; i < 8; ++i)
#pragma unroll
                for (int rr = 0; rr < 4; ++rr)
                    atomicAdd(&dst[m0 + wm * 128 + i * 16 + quad * 4 + rr], st[i][rr]);
        }
    }
}

// ---------------- ybar[b,d] += partial over a 32-step s chunk ----------------
// ybar[b,d] = (1/T) * sum_s ye[b,s,d] / max(||ye[b,s]||,1e-12); grid (B, 32).
__global__ void ybar_k(const ushort* __restrict__ G3, const float* __restrict__ sy,
                       float* __restrict__ ybar)
{
    int b = blockIdx.x, s0 = blockIdx.y * 32;
    int tid = threadIdx.x;
    __shared__ float sr[32];
    if (tid < 32) {
        float v = sy[b * TSEQ + s0 + tid];
        sr[tid] = (1.0f / TSEQ) / fmaxf(sqrtf(v), 1e-12f);
    }
    __syncthreads();
    float a0 = 0.f, a1 = 0.f, a2 = 0.f;
#pragma unroll 8
    for (int s = 0; s < 32; ++s) {
        const ushort* row = G3 + (size_t)(b * TSEQ + s0 + s) * NCAT + 2 * DDIM;
        float w = sr[s];
        a0 += b2f(row[tid])       * w;
        a1 += b2f(row[tid + 256]) * w;
        a2 += b2f(row[tid + 512]) * w;
    }
    atomicAdd(&ybar[b * DDIM + tid],       a0);
    atomicAdd(&ybar[b * DDIM + tid + 256], a1);
    atomicAdd(&ybar[b * DDIM + tid + 512], a2);
}

// ---------------- scores: wave-per-row, 4 rows/block (8192 blocks) ----------------
// scores[m] = rw0*(SE[m]+urb) + rw1 * dot(xe[m],ybar[b]) / max(sqrt(SX[m]),1e-12)
__global__ void pw_scores_k(const ushort* __restrict__ G3, const float* __restrict__ ybar,
                            const float* __restrict__ SE, const float* __restrict__ SX,
                            const float* __restrict__ urb, const float* __restrict__ red_w,
                            float* __restrict__ scores)
{
    int wv = threadIdx.x >> 6, lane = threadIdx.x & 63;
    int m = blockIdx.x * 4 + wv;
    int b = m >> 10;
    const ushort* xe = G3 + (size_t)m * NCAT + DDIM;
    const float4* yb = (const float4*)(ybar + b * DDIM);
    float s = 0.f;
#pragma unroll
    for (int c0 = 0; c0 < 3; ++c0) {
        int c = lane + c0 * 64;
        short4v v = *(const short4v*)(xe + c * 4);
        float4 yv = yb[c];
        s += b2f((ushort)v[0]) * yv.x + b2f((ushort)v[1]) * yv.y
           + b2f((ushort)v[2]) * yv.z + b2f((ushort)v[3]) * yv.w;
    }
#pragma unroll
    for (int off = 32; off; off >>= 1) s += __shfl_xor(s, off, 64);
    if (lane == 0) {
        float rnx = 1.f / fmaxf(sqrtf(SX[m]), 1e-12f);
        scores[m] = red_w[0] * (SE[m] + urb[0]) + red_w[1] * (rnx * s);
    }
}

// ---------------- out (with inline softmax): grid (B, 32) ----------------
// Each block recomputes batch-b softmax stats from scores (4 KB, L2-hit), then
// accumulates its 32-t chunk of out[b,:] = sum_t softmax(scores)[t] * u[b,t,:].
__global__ void out_sm_k(const ushort* __restrict__ U16, const float* __restrict__ scores,
                         float* __restrict__ out)
{
    int b = blockIdx.x, t0 = blockIdx.y * 32;
    int tid = threadIdx.x;
    int lane = tid & 63, wv = tid >> 6;
    __shared__ float red[8];
    __shared__ float sw[32];

    // block-wide softmax stats over scores[b, 0..1023]
    float v[4];
    float lm = -1e30f;
#pragma unroll
    for (int i = 0; i < 4; ++i) {
        v[i] = scores[b * TSEQ + i * 256 + tid];
        lm = fmaxf(lm, v[i]);
    }
#pragma unroll
    for (int off = 32; off; off >>= 1) lm = fmaxf(lm, __shfl_xor(lm, off, 64));
    if (lane == 0) red[wv] = lm;
    __syncthreads();
    float smax = fmaxf(fmaxf(red[0], red[1]), fmaxf(red[2], red[3]));
    float ls = 0.f;
#pragma unroll
    for (int i = 0; i < 4; ++i) ls += expf(v[i] - smax);
#pragma unroll
    for (int off = 32; off; off >>= 1) ls += __shfl_xor(ls, off, 64);
    if (lane == 0) red[4 + wv] = ls;
    __syncthreads();
    float inv = 1.f / (red[4] + red[5] + red[6] + red[7]);

    if (tid < 32) sw[tid] = expf(scores[b * TSEQ + t0 + tid] - smax) * inv;
    __syncthreads();

    float a0 = 0.f, a1 = 0.f, a2 = 0.f;
#pragma unroll 8
    for (int t = 0; t < 32; ++t) {
        const ushort* row = U16 + (size_t)(b * TSEQ + t0 + t) * DDIM;
        float w = sw[t];
        a0 += b2f(row[tid])       * w;
        a1 += b2f(row[tid + 256]) * w;
        a2 += b2f(row[tid + 512]) * w;
    }
    atomicAdd(&out[b * DDIM + tid],       a0);
    atomicAdd(&out[b * DDIM + tid + 256], a1);
    atomicAdd(&out[b * DDIM + tid + 512], a2);
}

// ---------------- workspace layout (bytes) ----------------
// G3 (e|xe|ye bf16, 151 MB) aliases the X16+H16 region (dead after GEMM2).
static const size_t O_X16   = 0;            // 32768*1536*2 = 100663296
static const size_t O_H16   = 100663296;    // 100663296
static const size_t O_G3    = 0;            // 150994944 (alias)
static const size_t O_U16   = 201326592;    // 50331648
static const size_t O_W1    = 251658240;    // 4718592
static const size_t O_W2    = 256376832;    // 2359296
static const size_t O_W3    = 258736128;    // 3538944
static const size_t O_B3    = 262275072;    // 9216
static const size_t O_SE    = 262284288;    // 131072  (SE/SX/SY contiguous)
static const size_t O_SX    = 262415360;    // 131072
static const size_t O_SY    = 262546432;    // 131072
static const size_t O_SCORE = 262677504;    // 131072
static const size_t O_YBAR  = 262939648;    // 98304
// total: 263037952 bytes (~263 MB)

extern "C" void kernel_launch(void* const* d_in, const int* in_sizes, int n_in,
                              void* d_out, int out_size, void* d_ws, size_t ws_size,
                              hipStream_t stream)
{
    const float* x        = (const float*)d_in[0];
    const float* fc1_w    = (const float*)d_in[1];
    const float* fc1_b    = (const float*)d_in[2];
    const float* fc2_w    = (const float*)d_in[3];
    const float* fc2_b    = (const float*)d_in[4];
    const float* un_emb_w = (const float*)d_in[5];
    const float* un_emb_b = (const float*)d_in[6];
    const float* un_red_w = (const float*)d_in[7];
    const float* un_red_b = (const float*)d_in[8];
    const float* pw_x_w   = (const float*)d_in[9];
    const float* pw_x_b   = (const float*)d_in[10];
    const float* pw_y_w   = (const float*)d_in[11];
    const float* pw_y_b   = (const float*)d_in[12];
    const float* red_w    = (const float*)d_in[13];

    char* ws = (char*)d_ws;
    ushort* X16 = (ushort*)(ws + O_X16);
    ushort* H16 = (ushort*)(ws + O_H16);
    ushort* G3  = (ushort*)(ws + O_G3);
    ushort* U16 = (ushort*)(ws + O_U16);
    ushort* W1  = (ushort*)(ws + O_W1);
    ushort* W2  = (ushort*)(ws + O_W2);
    ushort* W3  = (ushort*)(ws + O_W3);
    float*  B3  = (float*)(ws + O_B3);
    float*  SE  = (float*)(ws + O_SE);
    float*  SX  = (float*)(ws + O_SX);
    float*  SY  = (float*)(ws + O_SY);
    float*  SCORES = (float*)(ws + O_SCORE);
    float*  YBAR = (float*)(ws + O_YBAR);

    // --- one conversion/zeroing pass ---
    cvt_all<<<54483, 256, 0, stream>>>(x, fc1_w, fc2_w, un_emb_w, pw_x_w, pw_y_w,
                                       un_emb_b, pw_x_b, pw_y_b,
                                       X16, W1, W2, W3, B3, YBAR, (float*)d_out, SE);

    // --- GEMM chain (1-D grid, XCD-pinned swizzle inside kernel), 256^2 tiles ---
    gemm_bt<<<(MROWS / 256) * (INDIM / 256), 512, 0, stream>>>(
        X16, W1, fc1_b, H16, MROWS, INDIM, INDIM, INDIM,
        nullptr, nullptr, nullptr, nullptr);
    gemm_bt<<<(MROWS / 256) * (DDIM / 256), 512, 0, stream>>>(
        H16, W2, fc2_b, U16, MROWS, DDIM, INDIM, 0,
        nullptr, nullptr, nullptr, nullptr);
    gemm_bt<<<(MROWS / 256) * (NCAT / 256), 512, 0, stream>>>(
        U16, W3, B3, G3, MROWS, NCAT, DDIM, DDIM,
        un_red_w, SE, SX, SY);

    // --- tail: ybar -> scores -> out(+softmax), independent small launches ---
    ybar_k<<<dim3(BBATCH, 32), 256, 0, stream>>>(G3, SY, YBAR);
    pw_scores_k<<<MROWS / 4, 256, 0, stream>>>(G3, YBAR, SE, SX, un_red_b, red_w, SCORES);
    out_sm_k<<<dim3(BBATCH, 32), 256, 0, stream>>>(U16, SCORES, (float*)d_out);
}